// Round 2
// baseline (177.923 us; speedup 1.0000x reference)
//
#include <hip/hip_runtime.h>

// out[i,:] = mean_j(x[j,:]) @ Wv for all i (softmax with 2^-50 scale is exactly
// uniform in fp32; exp(|s|<6e-13) == 1.0f exactly). Q/K/Wq/Wk are dead.
//
// R2: grid.sync() ~100us each -> stream-ordered kernels.
// R3: global same-address atomicAdd ~100ns serialized -> zero atomics, tree reduce.
// R4: dur_us carries a fixed ~83us of harness 256-MiB d_ws poison fills
//     (2 x ~41.5us fillBuffer in the timed window). Controllable ~16.6us vs
//     ~12us serialized floor.
// R5: split-K matvec (256 blocks, float4 Wv loads) -> 99.6us.
// R6 (this round): remove one dispatch+gap: fuse colsum+matvec via a
//     completion ticket in ws. Blocks 0..255 prefetch Wv into regs at kernel
//     start (overlaps the x read), release-increment a counter after their
//     colsum phase, spin (acquire + s_sleep) until all 1024 blocks counted,
//     then run the matvec from registers. Counter base = poison value,
//     cancelled against an adjacent never-written ws word. Deadlock-free
//     (256 spinners << residency); bounded spin + recompute-from-x fallback
//     guarantees correctness even if ws were ever un-poisoned.

#define NROWS 8192
#define DDIM  1024
#define D4    (DDIM / 4)   // 256 float4 groups per row

typedef float f4 __attribute__((ext_vector_type(4)));

// ctrl words (uint32, in d_ws; poison fill re-initializes them each iteration):
//   ctrl[0] = cnt  (one release-increment per block)
//   ctrl[1] = done (one increment per mv block after spin-exit; enables cleanup)
//   ctrl[2] = ref  (never written; carries the uniform poison base value)

__global__ __launch_bounds__(256) void fused_k(
    const f4* __restrict__ x4, const f4* __restrict__ Wv4,
    f4* __restrict__ partial4, f4* __restrict__ outsplit4,
    unsigned int* __restrict__ ctrl) {
  __shared__ f4 red[256];     // 4 KB
  __shared__ f4 tmp[4][64];   // 4 KB
  __shared__ f4 cs4[64];      // 1 KB
  __shared__ int ok;
  const int t = threadIdx.x;
  const int b = blockIdx.x;
  const bool mv = (b < 256);          // matvec-designated blocks
  const int s   = b & 3;              // k-split      (mv blocks)
  const int cgv = b >> 2;             // d-colgroup   (mv blocks, [0,64))
  const int kf  = t >> 2;             // [0,64)
  const int dq  = t & 3;              // [0,4)

  // Wv prefetch for mv blocks: 4 MiB total, overlaps the 32 MiB x read.
  f4 w0, w1, w2, w3;
  if (mv) {
    const f4* wp = Wv4 + (size_t)(256 * s + kf) * D4 + 4 * cgv + dq;
    w0 = __builtin_nontemporal_load(wp);
    w1 = __builtin_nontemporal_load(wp + (size_t)64 * D4);
    w2 = __builtin_nontemporal_load(wp + (size_t)128 * D4);
    w3 = __builtin_nontemporal_load(wp + (size_t)192 * D4);
  }

  // Phase 1: partial column sums (identical to R5's colsum_part_k).
  // Block (rg=b>>4, cg=b&15) sums rows [128rg,128rg+128) x cols [64cg,64cg+64).
  {
    const int rg = b >> 4;
    const int cg = b & 15;
    const int cl = t & 15;
    const int rl = t >> 4;
    const f4* p = x4 + (size_t)(128 * rg + rl) * D4 + 16 * cg + cl;
    f4 acc = {0.f, 0.f, 0.f, 0.f};
#pragma unroll
    for (int j = 0; j < 8; ++j)
      acc += __builtin_nontemporal_load(&p[(size_t)(16 * j) * D4]);
    red[t] = acc;                     // layout t = rl*16 + cl
    __syncthreads();
    if (t < 128) red[t] += red[t + 128];
    __syncthreads();
    if (t < 64)  red[t] += red[t + 64];
    __syncthreads();
    if (t < 32)  red[t] += red[t + 32];
    __syncthreads();
    if (t < 16)  partial4[(size_t)rg * D4 + 16 * cg + t] = red[t] + red[t + 16];
    __syncthreads();  // all partial stores of this block done before release
  }

  if (t == 0) {
    (void)__hip_atomic_fetch_add(&ctrl[0], 1u, __ATOMIC_RELEASE,
                                 __HIP_MEMORY_SCOPE_AGENT);
  }
  if (!mv) return;

  // Spin until all 1024 blocks have released their partials.
  if (t == 0) {
    const unsigned ref = __hip_atomic_load(&ctrl[2], __ATOMIC_RELAXED,
                                           __HIP_MEMORY_SCOPE_AGENT);
    int good = 0;
    for (long it = 0; it < 4000000L; ++it) {   // ~1s bound; normal exit in <10us
      const unsigned c = __hip_atomic_load(&ctrl[0], __ATOMIC_ACQUIRE,
                                           __HIP_MEMORY_SCOPE_AGENT);
      if (c - ref == 1024u) { good = 1; break; }
      __builtin_amdgcn_s_sleep(2);
    }
    ok = good;
    if (good) {
      // Cleanup so a hypothetical non-repoisoned next launch starts clean:
      // last mv block to exit the spin restores cnt/done to the base value.
      const unsigned old = __hip_atomic_fetch_add(&ctrl[1], 1u, __ATOMIC_RELAXED,
                                                  __HIP_MEMORY_SCOPE_AGENT);
      if (old - ref == 255u) {
        __hip_atomic_store(&ctrl[0], ref, __ATOMIC_RELAXED, __HIP_MEMORY_SCOPE_AGENT);
        __hip_atomic_store(&ctrl[1], ref, __ATOMIC_RELAXED, __HIP_MEMORY_SCOPE_AGENT);
      }
    }
  }
  __syncthreads();

  // Step 1: reduce partial[64][k-range] -> cs4 (or fallback: recompute from x).
  {
    const int rq = t >> 6;    // [0,4)
    const int gl = t & 63;    // [0,64)
    f4 a = {0.f, 0.f, 0.f, 0.f};
    if (ok) {
#pragma unroll
      for (int m = 0; m < 16; ++m)
        a += partial4[(size_t)(rq * 16 + m) * D4 + 64 * s + gl];
    } else {
      // Correctness-only fallback (never taken when ws was poison-filled):
      // sum the full column slice directly from x.
      for (int r = rq; r < NROWS; r += 4)
        a += x4[(size_t)r * D4 + 64 * s + gl];
    }
    tmp[rq][gl] = a;
  }
  __syncthreads();
  if (t < 64) {
    const float sc = 1.0f / (float)NROWS;
    cs4[t] = (tmp[0][t] + tmp[1][t] + tmp[2][t] + tmp[3][t]) * sc;
  }
  __syncthreads();

  // Step 2: matvec from prefetched registers; reduce over kf; write outsplit.
  const float* cs = (const float*)cs4;   // local k' in [0,256)
  f4 acc = {0.f, 0.f, 0.f, 0.f};
  acc += w0 * cs[kf];
  acc += w1 * cs[kf + 64];
  acc += w2 * cs[kf + 128];
  acc += w3 * cs[kf + 192];
  red[t] = acc;             // layout t = kf*4 + dq; reduce over kf
  __syncthreads();
  if (t < 128) red[t] += red[t + 128];   // kf+32
  __syncthreads();
  if (t < 64)  red[t] += red[t + 64];    // kf+16
  __syncthreads();
  if (t < 32)  red[t] += red[t + 32];    // kf+8
  __syncthreads();
  if (t < 16)  red[t] += red[t + 16];    // kf+4
  __syncthreads();
  if (t < 8)   red[t] += red[t + 8];     // kf+2
  __syncthreads();
  if (t < 4)   outsplit4[(size_t)s * D4 + 4 * cgv + t] = red[t] + red[t + 4];
}

// K3: sum 4 k-splits (16 KB, L2-hot, once per block) and broadcast into all
// rows. 2048 blocks, 4 rows/block, float4 NT stores (write-bound; the extra
// L2 reads hide under the slower HBM write path).
__global__ __launch_bounds__(256) void bcast_k(
    const f4* __restrict__ outsplit4, f4* __restrict__ out4) {
  const int t = threadIdx.x;
  const int b = blockIdx.x;
  const f4 v = (outsplit4[t] + outsplit4[D4 + t]) +
               (outsplit4[2 * D4 + t] + outsplit4[3 * D4 + t]);
  f4* p = out4 + (size_t)b * 4 * D4 + t;
#pragma unroll
  for (int r = 0; r < 4; ++r) {
    __builtin_nontemporal_store(v, &p[(size_t)r * D4]);
  }
}

extern "C" void kernel_launch(void* const* d_in, const int* in_sizes, int n_in,
                              void* d_out, int out_size, void* d_ws, size_t ws_size,
                              hipStream_t stream) {
  const float* x  = (const float*)d_in[0];
  // d_in[1] = Wq, d_in[2] = Wk provably unused (softmax exactly uniform).
  const float* Wv = (const float*)d_in[3];
  float* ws       = (float*)d_ws;
  float* partial  = ws;                        // 64*1024 floats (256 KB)
  float* outsplit = ws + (size_t)64 * DDIM;    // 4*1024 floats  (16 KB)
  unsigned int* ctrl = (unsigned int*)(ws + (size_t)68 * 1024);  // 3 words

  hipLaunchKernelGGL(fused_k, dim3(1024), dim3(256), 0, stream,
                     (const f4*)x, (const f4*)Wv, (f4*)partial,
                     (f4*)outsplit, ctrl);
  hipLaunchKernelGGL(bcast_k, dim3(2048), dim3(256), 0, stream,
                     (const f4*)outsplit, (f4*)d_out);
}

// Round 3
// 170.149 us; speedup vs baseline: 1.0457x; 1.0457x over previous
//
#include <hip/hip_runtime.h>

// out[i,:] = mean_j(x[j,:]) @ Wv for all i (softmax with 2^-50 scale is exactly
// uniform in fp32; exp(|s|<6e-13) == 1.0f exactly). Q/K/Wq/Wk are dead.
//
// R2: grid.sync() ~100us each -> stream-ordered kernels.
// R3: global same-address atomicAdd ~100ns serialized -> zero atomics, tree reduce.
// R4: dur_us carries a fixed ~83us of harness 256-MiB d_ws poison fills.
//     Controllable ~16.6us vs ~12us serialized floor.
// R5: split-K matvec (256 blocks, float4 Wv loads) -> 99.6us.
// R6: fused colsum+matvec via completion ticket -> REGRESSED to 177.9us:
//     ACQUIRE atomic load per spin iteration emits a cache-invalidate
//     (agent scope on non-coherent per-XCD L2s); 256 waves x ~1000s of
//     iterations of buffer_inv thrashed every XCD's TCC (fused_k 94us,
//     VALUBusy 0.5%, 230 GB/s). Semantics were correct (absmax 0.0).
// R7 (this round): spin with RELAXED loads (plain coherence-point load, no
//     invalidate) + ONE acquire load after success as the fence. Producer
//     release fetch_add unchanged (one L2 writeback per block, cheap).

#define NROWS 8192
#define DDIM  1024
#define D4    (DDIM / 4)   // 256 float4 groups per row

typedef float f4 __attribute__((ext_vector_type(4)));

// ctrl words (uint32, in d_ws; poison fill re-initializes them each iteration):
//   ctrl[0] = cnt  (one release-increment per block)
//   ctrl[1] = done (one increment per mv block after spin-exit; enables cleanup)
//   ctrl[2] = ref  (never written; carries the uniform poison base value)

__global__ __launch_bounds__(256) void fused_k(
    const f4* __restrict__ x4, const f4* __restrict__ Wv4,
    f4* __restrict__ partial4, f4* __restrict__ outsplit4,
    unsigned int* __restrict__ ctrl) {
  __shared__ f4 red[256];     // 4 KB
  __shared__ f4 tmp[4][64];   // 4 KB
  __shared__ f4 cs4[64];      // 1 KB
  __shared__ int ok;
  const int t = threadIdx.x;
  const int b = blockIdx.x;
  const bool mv = (b < 256);          // matvec-designated blocks
  const int s   = b & 3;              // k-split      (mv blocks)
  const int cgv = b >> 2;             // d-colgroup   (mv blocks, [0,64))
  const int kf  = t >> 2;             // [0,64)
  const int dq  = t & 3;              // [0,4)

  // Wv prefetch for mv blocks: 4 MiB total, overlaps the 32 MiB x read.
  f4 w0, w1, w2, w3;
  if (mv) {
    const f4* wp = Wv4 + (size_t)(256 * s + kf) * D4 + 4 * cgv + dq;
    w0 = __builtin_nontemporal_load(wp);
    w1 = __builtin_nontemporal_load(wp + (size_t)64 * D4);
    w2 = __builtin_nontemporal_load(wp + (size_t)128 * D4);
    w3 = __builtin_nontemporal_load(wp + (size_t)192 * D4);
  }

  // Phase 1: partial column sums.
  // Block (rg=b>>4, cg=b&15) sums rows [128rg,128rg+128) x cols [64cg,64cg+64).
  {
    const int rg = b >> 4;
    const int cg = b & 15;
    const int cl = t & 15;
    const int rl = t >> 4;
    const f4* p = x4 + (size_t)(128 * rg + rl) * D4 + 16 * cg + cl;
    f4 acc = {0.f, 0.f, 0.f, 0.f};
#pragma unroll
    for (int j = 0; j < 8; ++j)
      acc += __builtin_nontemporal_load(&p[(size_t)(16 * j) * D4]);
    red[t] = acc;                     // layout t = rl*16 + cl
    __syncthreads();
    if (t < 128) red[t] += red[t + 128];
    __syncthreads();
    if (t < 64)  red[t] += red[t + 64];
    __syncthreads();
    if (t < 32)  red[t] += red[t + 32];
    __syncthreads();
    if (t < 16)  partial4[(size_t)rg * D4 + 16 * cg + t] = red[t] + red[t + 16];
    __syncthreads();  // all partial stores of this block done before release
  }

  if (t == 0) {
    (void)__hip_atomic_fetch_add(&ctrl[0], 1u, __ATOMIC_RELEASE,
                                 __HIP_MEMORY_SCOPE_AGENT);
  }
  if (!mv) return;

  // Spin with RELAXED loads (no cache-invalidate per iteration!) until all
  // 1024 blocks have released their partials, then ONE acquire as the fence.
  if (t == 0) {
    const unsigned ref = __hip_atomic_load(&ctrl[2], __ATOMIC_RELAXED,
                                           __HIP_MEMORY_SCOPE_AGENT);
    int good = 0;
    for (long it = 0; it < 1048576L; ++it) {   // ~0.1s bound; normal exit <10us
      const unsigned c = __hip_atomic_load(&ctrl[0], __ATOMIC_RELAXED,
                                           __HIP_MEMORY_SCOPE_AGENT);
      if (c - ref == 1024u) { good = 1; break; }
      __builtin_amdgcn_s_sleep(4);
    }
    if (good) {
      // Single acquire fence: makes producers' partial stores visible.
      (void)__hip_atomic_load(&ctrl[0], __ATOMIC_ACQUIRE,
                              __HIP_MEMORY_SCOPE_AGENT);
      // Cleanup so a hypothetical non-repoisoned next launch starts clean:
      // last mv block to exit the spin restores cnt/done to the base value.
      const unsigned old = __hip_atomic_fetch_add(&ctrl[1], 1u, __ATOMIC_RELAXED,
                                                  __HIP_MEMORY_SCOPE_AGENT);
      if (old - ref == 255u) {
        __hip_atomic_store(&ctrl[0], ref, __ATOMIC_RELAXED, __HIP_MEMORY_SCOPE_AGENT);
        __hip_atomic_store(&ctrl[1], ref, __ATOMIC_RELAXED, __HIP_MEMORY_SCOPE_AGENT);
      }
    }
    ok = good;
  }
  __syncthreads();

  // Step 1: reduce partial[64][k-range] -> cs4 (or fallback: recompute from x).
  {
    const int rq = t >> 6;    // [0,4)
    const int gl = t & 63;    // [0,64)
    f4 a = {0.f, 0.f, 0.f, 0.f};
    if (ok) {
#pragma unroll
      for (int m = 0; m < 16; ++m)
        a += partial4[(size_t)(rq * 16 + m) * D4 + 64 * s + gl];
    } else {
      // Correctness-only fallback (never taken when ws was poison-filled):
      // sum the full column slice directly from x.
      for (int r = rq; r < NROWS; r += 4)
        a += x4[(size_t)r * D4 + 64 * s + gl];
    }
    tmp[rq][gl] = a;
  }
  __syncthreads();
  if (t < 64) {
    const float sc = 1.0f / (float)NROWS;
    cs4[t] = (tmp[0][t] + tmp[1][t] + tmp[2][t] + tmp[3][t]) * sc;
  }
  __syncthreads();

  // Step 2: matvec from prefetched registers; reduce over kf; write outsplit.
  const float* cs = (const float*)cs4;   // local k' in [0,256)
  f4 acc = {0.f, 0.f, 0.f, 0.f};
  acc += w0 * cs[kf];
  acc += w1 * cs[kf + 64];
  acc += w2 * cs[kf + 128];
  acc += w3 * cs[kf + 192];
  red[t] = acc;             // layout t = kf*4 + dq; reduce over kf
  __syncthreads();
  if (t < 128) red[t] += red[t + 128];   // kf+32
  __syncthreads();
  if (t < 64)  red[t] += red[t + 64];    // kf+16
  __syncthreads();
  if (t < 32)  red[t] += red[t + 32];    // kf+8
  __syncthreads();
  if (t < 16)  red[t] += red[t + 16];    // kf+4
  __syncthreads();
  if (t < 8)   red[t] += red[t + 8];     // kf+2
  __syncthreads();
  if (t < 4)   outsplit4[(size_t)s * D4 + 4 * cgv + t] = red[t] + red[t + 4];
}

// K3: sum 4 k-splits (16 KB, L2-hot, once per block) and broadcast into all
// rows. 2048 blocks, 4 rows/block, float4 NT stores (write-bound; the extra
// L2 reads hide under the slower HBM write path).
__global__ __launch_bounds__(256) void bcast_k(
    const f4* __restrict__ outsplit4, f4* __restrict__ out4) {
  const int t = threadIdx.x;
  const int b = blockIdx.x;
  const f4 v = (outsplit4[t] + outsplit4[D4 + t]) +
               (outsplit4[2 * D4 + t] + outsplit4[3 * D4 + t]);
  f4* p = out4 + (size_t)b * 4 * D4 + t;
#pragma unroll
  for (int r = 0; r < 4; ++r) {
    __builtin_nontemporal_store(v, &p[(size_t)r * D4]);
  }
}

extern "C" void kernel_launch(void* const* d_in, const int* in_sizes, int n_in,
                              void* d_out, int out_size, void* d_ws, size_t ws_size,
                              hipStream_t stream) {
  const float* x  = (const float*)d_in[0];
  // d_in[1] = Wq, d_in[2] = Wk provably unused (softmax exactly uniform).
  const float* Wv = (const float*)d_in[3];
  float* ws       = (float*)d_ws;
  float* partial  = ws;                        // 64*1024 floats (256 KB)
  float* outsplit = ws + (size_t)64 * DDIM;    // 4*1024 floats  (16 KB)
  unsigned int* ctrl = (unsigned int*)(ws + (size_t)68 * 1024);  // 3 words

  hipLaunchKernelGGL(fused_k, dim3(1024), dim3(256), 0, stream,
                     (const f4*)x, (const f4*)Wv, (f4*)partial,
                     (f4*)outsplit, ctrl);
  hipLaunchKernelGGL(bcast_k, dim3(2048), dim3(256), 0, stream,
                     (const f4*)outsplit, (f4*)d_out);
}

// Round 4
// 129.224 us; speedup vs baseline: 1.3769x; 1.3167x over previous
//
#include <hip/hip_runtime.h>

// out[i,:] = mean_j(x[j,:]) @ Wv for all i (softmax with 2^-50 scale is exactly
// uniform in fp32; exp(|s|<6e-13) == 1.0f exactly). Q/K/Wq/Wk are dead.
//
// R2: grid.sync() ~100us each -> stream-ordered kernels.
// R3: global same-address atomicAdd ~100ns serialized -> zero atomics, tree reduce.
// R4: dur_us carries a fixed ~83us of harness 256-MiB d_ws poison fills.
//     Controllable ~16.6us vs ~12us serialized floor.
// R5: split-K matvec (256 blocks, float4 Wv loads) -> 99.6us.
// R6: fused colsum+matvec via single-counter ticket -> 177.9us. Theory
//     "acquire-spin invalidates" DISPROVEN by R7:
// R7: relaxed-spin identical (88us fused_k, VALUBusy 0.5%). Real cause is the
//     R3 lesson again: 1024 same-address agent fetch_adds serialize at
//     ~86ns each = 88us. The spin flavor never mattered.
// R8 (this round): zero same-address RMWs. Per-block RELEASE store of ref+1
//     into flags[1024] (independent words, parallel); mv blocks poll flags
//     with relaxed agent loads + one ACQUIRE fence on success (pattern whose
//     correctness R6/R7 proved). No cleanup needed: without re-poison, flags
//     already equal ref+1 and partial holds bit-identical values -> still
//     exact. Bounded poll + recompute-from-x fallback retained.

#define NROWS 8192
#define DDIM  1024
#define D4    (DDIM / 4)   // 256 float4 groups per row

typedef float f4 __attribute__((ext_vector_type(4)));

// ws layout (floats):
//   partial  @ 0       : 64*1024 floats (256 KB)
//   outsplit @ 65536   : 4*1024 floats  (16 KB)
//   flags    @ 69632   : 1024 uint32    (4 KB)   one per block
//   ref      @ 70656   : 1 uint32, never written (uniform poison base)

__global__ __launch_bounds__(256) void fused_k(
    const f4* __restrict__ x4, const f4* __restrict__ Wv4,
    f4* __restrict__ partial4, f4* __restrict__ outsplit4,
    unsigned int* __restrict__ flags, const unsigned int* __restrict__ refw) {
  __shared__ f4 red[256];     // 4 KB
  __shared__ f4 tmp[4][64];   // 4 KB
  __shared__ f4 cs4[64];      // 1 KB
  __shared__ int oks;
  const int t = threadIdx.x;
  const int b = blockIdx.x;
  const bool mv = (b < 256);          // matvec-designated blocks
  const int s   = b & 3;              // k-split      (mv blocks)
  const int cgv = b >> 2;             // d-colgroup   (mv blocks, [0,64))
  const int kf  = t >> 2;             // [0,64)
  const int dq  = t & 3;              // [0,4)

  if (t == 0) oks = 1;   // made visible by the colsum-phase __syncthreads

  // Wv prefetch for mv blocks: 4 MiB total, overlaps the 32 MiB x read.
  f4 w0, w1, w2, w3;
  if (mv) {
    const f4* wp = Wv4 + (size_t)(256 * s + kf) * D4 + 4 * cgv + dq;
    w0 = __builtin_nontemporal_load(wp);
    w1 = __builtin_nontemporal_load(wp + (size_t)64 * D4);
    w2 = __builtin_nontemporal_load(wp + (size_t)128 * D4);
    w3 = __builtin_nontemporal_load(wp + (size_t)192 * D4);
  }

  // Phase 1: partial column sums.
  // Block (rg=b>>4, cg=b&15) sums rows [128rg,128rg+128) x cols [64cg,64cg+64).
  {
    const int rg = b >> 4;
    const int cg = b & 15;
    const int cl = t & 15;
    const int rl = t >> 4;
    const f4* p = x4 + (size_t)(128 * rg + rl) * D4 + 16 * cg + cl;
    f4 acc = {0.f, 0.f, 0.f, 0.f};
#pragma unroll
    for (int j = 0; j < 8; ++j)
      acc += __builtin_nontemporal_load(&p[(size_t)(16 * j) * D4]);
    red[t] = acc;                     // layout t = rl*16 + cl
    __syncthreads();
    if (t < 128) red[t] += red[t + 128];
    __syncthreads();
    if (t < 64)  red[t] += red[t + 64];
    __syncthreads();
    if (t < 32)  red[t] += red[t + 32];
    __syncthreads();
    if (t < 16)  partial4[(size_t)rg * D4 + 16 * cg + t] = red[t] + red[t + 16];
    __syncthreads();  // all partial stores of this block done before release
  }

  // Publish: one RELEASE store per block to its own flag word. Independent
  // addresses -> no serialization (R6/R7 killer). Release fence publishes
  // this block's partial tile (same fence the R6/R7 fetch_add proved).
  if (t == 0) {
    const unsigned ref = __hip_atomic_load(refw, __ATOMIC_RELAXED,
                                           __HIP_MEMORY_SCOPE_AGENT);
    __hip_atomic_store(&flags[b], ref + 1u, __ATOMIC_RELEASE,
                       __HIP_MEMORY_SCOPE_AGENT);
  }
  if (!mv) return;

  // Poll all 1024 flags: thread t owns flags[t + 256k], k<4. Relaxed agent
  // loads (no invalidate traffic); s_sleep between rounds.
  {
    const unsigned ref = __hip_atomic_load(refw, __ATOMIC_RELAXED,
                                           __HIP_MEMORY_SCOPE_AGENT);
    const unsigned tgt = ref + 1u;
    int good = 0;
    for (int it = 0; it < 50000; ++it) {   // ~20ms bound; normal exit in ~1us
      const unsigned a0 = __hip_atomic_load(&flags[t], __ATOMIC_RELAXED,
                                            __HIP_MEMORY_SCOPE_AGENT);
      const unsigned a1 = __hip_atomic_load(&flags[t + 256], __ATOMIC_RELAXED,
                                            __HIP_MEMORY_SCOPE_AGENT);
      const unsigned a2 = __hip_atomic_load(&flags[t + 512], __ATOMIC_RELAXED,
                                            __HIP_MEMORY_SCOPE_AGENT);
      const unsigned a3 = __hip_atomic_load(&flags[t + 768], __ATOMIC_RELAXED,
                                            __HIP_MEMORY_SCOPE_AGENT);
      if (a0 == tgt && a1 == tgt && a2 == tgt && a3 == tgt) { good = 1; break; }
      __builtin_amdgcn_s_sleep(8);
    }
    if (!good) oks = 0;   // race-benign: any writer writes 0
  }
  __syncthreads();
  const int ok = oks;
  if (ok && t == 0) {
    // Single acquire fence: makes producers' partial stores visible
    // (exact pattern validated in R6/R7, absmax 0.0).
    (void)__hip_atomic_load(&flags[0], __ATOMIC_ACQUIRE,
                            __HIP_MEMORY_SCOPE_AGENT);
  }
  __syncthreads();

  // Step 1: reduce partial[64][k-range] -> cs4 (or fallback: recompute from x).
  {
    const int rq = t >> 6;    // [0,4)
    const int gl = t & 63;    // [0,64)
    f4 a = {0.f, 0.f, 0.f, 0.f};
    if (ok) {
#pragma unroll
      for (int m = 0; m < 16; ++m)
        a += partial4[(size_t)(rq * 16 + m) * D4 + 64 * s + gl];
    } else {
      // Correctness-only fallback (timeout path): sum column slice from x.
      for (int r = rq; r < NROWS; r += 4)
        a += x4[(size_t)r * D4 + 64 * s + gl];
    }
    tmp[rq][gl] = a;
  }
  __syncthreads();
  if (t < 64) {
    const float sc = 1.0f / (float)NROWS;
    cs4[t] = (tmp[0][t] + tmp[1][t] + tmp[2][t] + tmp[3][t]) * sc;
  }
  __syncthreads();

  // Step 2: matvec from prefetched registers; reduce over kf; write outsplit.
  const float* cs = (const float*)cs4;   // local k' in [0,256)
  f4 acc = {0.f, 0.f, 0.f, 0.f};
  acc += w0 * cs[kf];
  acc += w1 * cs[kf + 64];
  acc += w2 * cs[kf + 128];
  acc += w3 * cs[kf + 192];
  red[t] = acc;             // layout t = kf*4 + dq; reduce over kf
  __syncthreads();
  if (t < 128) red[t] += red[t + 128];   // kf+32
  __syncthreads();
  if (t < 64)  red[t] += red[t + 64];    // kf+16
  __syncthreads();
  if (t < 32)  red[t] += red[t + 32];    // kf+8
  __syncthreads();
  if (t < 16)  red[t] += red[t + 16];    // kf+4
  __syncthreads();
  if (t < 8)   red[t] += red[t + 8];     // kf+2
  __syncthreads();
  if (t < 4)   outsplit4[(size_t)s * D4 + 4 * cgv + t] = red[t] + red[t + 4];
}

// K3: sum 4 k-splits (16 KB, L2-hot, once per block) and broadcast into all
// rows. 2048 blocks, 4 rows/block, float4 NT stores (write-bound; the extra
// L2 reads hide under the slower HBM write path).
__global__ __launch_bounds__(256) void bcast_k(
    const f4* __restrict__ outsplit4, f4* __restrict__ out4) {
  const int t = threadIdx.x;
  const int b = blockIdx.x;
  const f4 v = (outsplit4[t] + outsplit4[D4 + t]) +
               (outsplit4[2 * D4 + t] + outsplit4[3 * D4 + t]);
  f4* p = out4 + (size_t)b * 4 * D4 + t;
#pragma unroll
  for (int r = 0; r < 4; ++r) {
    __builtin_nontemporal_store(v, &p[(size_t)r * D4]);
  }
}

extern "C" void kernel_launch(void* const* d_in, const int* in_sizes, int n_in,
                              void* d_out, int out_size, void* d_ws, size_t ws_size,
                              hipStream_t stream) {
  const float* x  = (const float*)d_in[0];
  // d_in[1] = Wq, d_in[2] = Wk provably unused (softmax exactly uniform).
  const float* Wv = (const float*)d_in[3];
  float* ws       = (float*)d_ws;
  float* partial  = ws;                           // 65536 floats (256 KB)
  float* outsplit = ws + (size_t)64 * DDIM;       // 4096 floats  (16 KB)
  unsigned int* flags = (unsigned int*)(ws + (size_t)68 * 1024);  // 1024 words
  const unsigned int* refw = (const unsigned int*)(ws + (size_t)69 * 1024);

  hipLaunchKernelGGL(fused_k, dim3(1024), dim3(256), 0, stream,
                     (const f4*)x, (const f4*)Wv, (f4*)partial,
                     (f4*)outsplit, flags, refw);
  hipLaunchKernelGGL(bcast_k, dim3(2048), dim3(256), 0, stream,
                     (const f4*)outsplit, (f4*)d_out);
}

// Round 5
// 125.984 us; speedup vs baseline: 1.4123x; 1.0257x over previous
//
#include <hip/hip_runtime.h>

// out[i,:] = mean_j(x[j,:]) @ Wv for all i (softmax with 2^-50 scale is exactly
// uniform in fp32; exp(|s|<6e-13) == 1.0f exactly). Q/K/Wq/Wk are dead.
//
// R2: grid.sync() ~100us each -> stream-ordered kernels.
// R3: global same-address atomicAdd ~100ns serialized -> zero atomics, tree reduce.
// R4: ~83us fixed harness poison fills in the timed window; floor ~12us.
// R5: split-K matvec, 3 kernels -> 99.6us (controllable ~16.6us).
// R6: fused w/ single-counter ticket -> 177.9us (1024 same-addr fetch_adds
//     serialize ~86ns each; spin flavor irrelevant, proven by R7).
// R7: relaxed-spin identical -> theory corrected to RMW serialization.
// R8: per-block flag array -> 129.2us (fused_k 88->45us). Replay dispatches
//     show 45us even with x L3-resident (hbm_bytes 0.3MB) -> not fetch-bound:
//     65536 polling threads x 4 agent loads/0.2us flood the coherence point,
//     starving producers (~750 GB/s effective x-read).
// R9 (this round): hierarchical completion. Only block 0 polls the 1024 flags
//     (256 threads + __syncthreads_and, s_sleep rounds), then release-stores
//     ONE superflag; mv blocks poll the superflag with ONE thread each.
//     Pollers 65536 -> ~257, poll traffic ~200x down. Fence pattern (relaxed
//     observe -> one ACQUIRE load -> __syncthreads) unchanged from R6-R8
//     (absmax 0.0 three rounds running). Timeout + recompute-from-x fallback.

#define NROWS 8192
#define DDIM  1024
#define D4    (DDIM / 4)   // 256 float4 groups per row

typedef float f4 __attribute__((ext_vector_type(4)));

// ws layout (floats):
//   partial   @ 0     : 64*1024 floats (256 KB)
//   outsplit  @ 65536 : 4*1024 floats  (16 KB)
//   flags     @ 69632 : 1024 uint32 (4 KB), one per block
//   superflag @ 70656 : 1 uint32
//   ref       @ 70657 : 1 uint32, never written (uniform poison base)

__global__ __launch_bounds__(256) void fused_k(
    const f4* __restrict__ x4, const f4* __restrict__ Wv4,
    f4* __restrict__ partial4, f4* __restrict__ outsplit4,
    unsigned int* __restrict__ flags, unsigned int* __restrict__ super,
    const unsigned int* __restrict__ refw) {
  __shared__ f4 red[256];     // 4 KB
  __shared__ f4 tmp[4][64];   // 4 KB
  __shared__ f4 cs4[64];      // 1 KB
  __shared__ int oks;
  const int t = threadIdx.x;
  const int b = blockIdx.x;
  const bool mv = (b < 256);          // matvec-designated blocks
  const int s   = b & 3;              // k-split      (mv blocks)
  const int cgv = b >> 2;             // d-colgroup   (mv blocks, [0,64))
  const int kf  = t >> 2;             // [0,64)
  const int dq  = t & 3;              // [0,4)

  // Wv prefetch for mv blocks: 4 MiB total, overlaps the 32 MiB x read.
  f4 w0, w1, w2, w3;
  if (mv) {
    const f4* wp = Wv4 + (size_t)(256 * s + kf) * D4 + 4 * cgv + dq;
    w0 = __builtin_nontemporal_load(wp);
    w1 = __builtin_nontemporal_load(wp + (size_t)64 * D4);
    w2 = __builtin_nontemporal_load(wp + (size_t)128 * D4);
    w3 = __builtin_nontemporal_load(wp + (size_t)192 * D4);
  }

  // Phase 1: partial column sums.
  // Block (rg=b>>4, cg=b&15) sums rows [128rg,128rg+128) x cols [64cg,64cg+64).
  {
    const int rg = b >> 4;
    const int cg = b & 15;
    const int cl = t & 15;
    const int rl = t >> 4;
    const f4* p = x4 + (size_t)(128 * rg + rl) * D4 + 16 * cg + cl;
    f4 acc = {0.f, 0.f, 0.f, 0.f};
#pragma unroll
    for (int j = 0; j < 8; ++j)
      acc += __builtin_nontemporal_load(&p[(size_t)(16 * j) * D4]);
    red[t] = acc;                     // layout t = rl*16 + cl
    __syncthreads();
    if (t < 128) red[t] += red[t + 128];
    __syncthreads();
    if (t < 64)  red[t] += red[t + 64];
    __syncthreads();
    if (t < 32)  red[t] += red[t + 32];
    __syncthreads();
    if (t < 16)  partial4[(size_t)rg * D4 + 16 * cg + t] = red[t] + red[t + 16];
    __syncthreads();  // all partial stores of this block done before release
  }

  const unsigned ref = __hip_atomic_load(refw, __ATOMIC_RELAXED,
                                         __HIP_MEMORY_SCOPE_AGENT);
  const unsigned tgt = ref + 1u;

  // Publish: one RELEASE store per block to its own flag word (independent
  // addresses -> parallel; release publishes this block's partial tile).
  if (t == 0) {
    __hip_atomic_store(&flags[b], tgt, __ATOMIC_RELEASE,
                       __HIP_MEMORY_SCOPE_AGENT);
  }

  // Level 1: ONLY block 0 polls the flag array, then raises the superflag.
  if (b == 0) {
    int good = 0;
    for (int it = 0; it < 200000; ++it) {   // ~60ms bound; normal exit ~1-2 rounds
      const unsigned a0 = __hip_atomic_load(&flags[t], __ATOMIC_RELAXED,
                                            __HIP_MEMORY_SCOPE_AGENT);
      const unsigned a1 = __hip_atomic_load(&flags[t + 256], __ATOMIC_RELAXED,
                                            __HIP_MEMORY_SCOPE_AGENT);
      const unsigned a2 = __hip_atomic_load(&flags[t + 512], __ATOMIC_RELAXED,
                                            __HIP_MEMORY_SCOPE_AGENT);
      const unsigned a3 = __hip_atomic_load(&flags[t + 768], __ATOMIC_RELAXED,
                                            __HIP_MEMORY_SCOPE_AGENT);
      const int mine = (a0 == tgt) & (a1 == tgt) & (a2 == tgt) & (a3 == tgt);
      if (__syncthreads_and(mine)) { good = 1; break; }
      __builtin_amdgcn_s_sleep(4);
    }
    if (t == 0 && good) {
      __hip_atomic_store(super, tgt, __ATOMIC_RELEASE,
                         __HIP_MEMORY_SCOPE_AGENT);
    }
  }
  if (!mv) return;

  // Level 2: one thread per mv block polls the single superflag word.
  if (t == 0) {
    int good = 0;
    for (int it = 0; it < 400000; ++it) {   // bound; normal exit in ~1-3us
      const unsigned sv = __hip_atomic_load(super, __ATOMIC_RELAXED,
                                            __HIP_MEMORY_SCOPE_AGENT);
      if (sv == tgt) { good = 1; break; }
      __builtin_amdgcn_s_sleep(6);
    }
    if (good) {
      // Single acquire fence: makes producers' partial stores visible
      // (pattern validated R6-R8, absmax 0.0).
      (void)__hip_atomic_load(super, __ATOMIC_ACQUIRE,
                              __HIP_MEMORY_SCOPE_AGENT);
    }
    oks = good;
  }
  __syncthreads();
  const int ok = oks;

  // Step 1: reduce partial[64][k-range] -> cs4 (or fallback: recompute from x).
  {
    const int rq = t >> 6;    // [0,4)
    const int gl = t & 63;    // [0,64)
    f4 a = {0.f, 0.f, 0.f, 0.f};
    if (ok) {
#pragma unroll
      for (int m = 0; m < 16; ++m)
        a += partial4[(size_t)(rq * 16 + m) * D4 + 64 * s + gl];
    } else {
      // Correctness-only fallback (timeout path): sum column slice from x.
      for (int r = rq; r < NROWS; r += 4)
        a += x4[(size_t)r * D4 + 64 * s + gl];
    }
    tmp[rq][gl] = a;
  }
  __syncthreads();
  if (t < 64) {
    const float sc = 1.0f / (float)NROWS;
    cs4[t] = (tmp[0][t] + tmp[1][t] + tmp[2][t] + tmp[3][t]) * sc;
  }
  __syncthreads();

  // Step 2: matvec from prefetched registers; reduce over kf; write outsplit.
  const float* cs = (const float*)cs4;   // local k' in [0,256)
  f4 acc = {0.f, 0.f, 0.f, 0.f};
  acc += w0 * cs[kf];
  acc += w1 * cs[kf + 64];
  acc += w2 * cs[kf + 128];
  acc += w3 * cs[kf + 192];
  red[t] = acc;             // layout t = kf*4 + dq; reduce over kf
  __syncthreads();
  if (t < 128) red[t] += red[t + 128];   // kf+32
  __syncthreads();
  if (t < 64)  red[t] += red[t + 64];    // kf+16
  __syncthreads();
  if (t < 32)  red[t] += red[t + 32];    // kf+8
  __syncthreads();
  if (t < 16)  red[t] += red[t + 16];    // kf+4
  __syncthreads();
  if (t < 8)   red[t] += red[t + 8];     // kf+2
  __syncthreads();
  if (t < 4)   outsplit4[(size_t)s * D4 + 4 * cgv + t] = red[t] + red[t + 4];
}

// K3: sum 4 k-splits (16 KB, L2-hot, once per block) and broadcast into all
// rows. 2048 blocks, 4 rows/block, float4 NT stores (write-bound; the extra
// L2 reads hide under the slower HBM write path).
__global__ __launch_bounds__(256) void bcast_k(
    const f4* __restrict__ outsplit4, f4* __restrict__ out4) {
  const int t = threadIdx.x;
  const int b = blockIdx.x;
  const f4 v = (outsplit4[t] + outsplit4[D4 + t]) +
               (outsplit4[2 * D4 + t] + outsplit4[3 * D4 + t]);
  f4* p = out4 + (size_t)b * 4 * D4 + t;
#pragma unroll
  for (int r = 0; r < 4; ++r) {
    __builtin_nontemporal_store(v, &p[(size_t)r * D4]);
  }
}

extern "C" void kernel_launch(void* const* d_in, const int* in_sizes, int n_in,
                              void* d_out, int out_size, void* d_ws, size_t ws_size,
                              hipStream_t stream) {
  const float* x  = (const float*)d_in[0];
  // d_in[1] = Wq, d_in[2] = Wk provably unused (softmax exactly uniform).
  const float* Wv = (const float*)d_in[3];
  float* ws       = (float*)d_ws;
  float* partial  = ws;                           // 65536 floats (256 KB)
  float* outsplit = ws + (size_t)64 * DDIM;       // 4096 floats  (16 KB)
  unsigned int* flags = (unsigned int*)(ws + (size_t)68 * 1024);  // 1024 words
  unsigned int* super = flags + 1024;
  const unsigned int* refw = (const unsigned int*)(super + 1);

  hipLaunchKernelGGL(fused_k, dim3(1024), dim3(256), 0, stream,
                     (const f4*)x, (const f4*)Wv, (f4*)partial,
                     (f4*)outsplit, flags, super, refw);
  hipLaunchKernelGGL(bcast_k, dim3(2048), dim3(256), 0, stream,
                     (const f4*)outsplit, (f4*)d_out);
}

// Round 6
// 101.525 us; speedup vs baseline: 1.7525x; 1.2409x over previous
//
#include <hip/hip_runtime.h>

// out[i,:] = mean_j(x[j,:]) @ Wv for all i (softmax with 2^-50 scale is exactly
// uniform in fp32; exp(|s|<6e-13) == 1.0f exactly). Q/K/Wq/Wk are dead.
//
// R2: grid.sync() ~100us each -> stream-ordered kernels.
// R3: global same-address atomicAdd ~100ns serialized -> zero atomics.
// R4: ~83us fixed harness poison fills in the timed window; floor ~12us.
// R5: split-K matvec, 3 kernels -> 99.6us (controllable ~16.6us).
// R6/R7: fused w/ counter ticket -> 178/170us: 1024 same-addr RMWs serialize.
// R8: per-block flag array -> 129us (fused_k 45us, even with x L3-resident).
// R9: hierarchical poll (65536 -> 257 pollers) -> NO CHANGE (44us). Poll
//     volume twice ruled out. Remaining cost common to R6-R9, absent in R5:
//     agent-scope RELEASE stores emit buffer_wbl2 (full per-XCD L2 writeback
//     walk) and ACQUIREs emit buffer_inv. 1024 wbl2 / 8 XCDs = 128 walks/XCD
//     x ~350ns ~= 44us. Matches all four rounds (R6/R7 = walks + RMW).
// R10 (this round): ZERO cache-maintenance sync. All cross-block traffic is
//     per-instruction L2-bypassing (sc0 sc1 = write-through/read-through the
//     L3 coherence point): partial stores + flag store via asm sc0 sc1 with
//     one wave-0 vmcnt(0) between (intra-wave program order = the fence);
//     consumers read partial via asm sc0 sc1 loads. No wbl2, no inv, no
//     RELEASE, no ACQUIRE. L3 is the single coherence point: flag-in-L3
//     implies data-in-L3. Timeout + recompute-from-x fallback retained.

#define NROWS 8192
#define DDIM  1024
#define D4    (DDIM / 4)   // 256 float4 groups per row

typedef float f4 __attribute__((ext_vector_type(4)));

// ws layout (floats):
//   partial   @ 0     : 64*1024 floats (256 KB)
//   outsplit  @ 65536 : 4*1024 floats  (16 KB)
//   flags     @ 69632 : 1024 uint32 (4 KB), one per block
//   superflag @ 70656 : 1 uint32
//   ref       @ 70657 : 1 uint32, never written (uniform poison base)

__global__ __launch_bounds__(256) void fused_k(
    const f4* __restrict__ x4, const f4* __restrict__ Wv4,
    f4* __restrict__ partial4, f4* __restrict__ outsplit4,
    unsigned int* __restrict__ flags, unsigned int* __restrict__ super,
    const unsigned int* __restrict__ refw) {
  __shared__ f4 red[256];     // 4 KB
  __shared__ f4 tmp[4][64];   // 4 KB
  __shared__ f4 cs4[64];      // 1 KB
  __shared__ int oks;
  const int t = threadIdx.x;
  const int b = blockIdx.x;
  const bool mv = (b < 256);          // matvec-designated blocks
  const int s   = b & 3;              // k-split      (mv blocks)
  const int cgv = b >> 2;             // d-colgroup   (mv blocks, [0,64))
  const int kf  = t >> 2;             // [0,64)
  const int dq  = t & 3;              // [0,4)

  // Wv prefetch for mv blocks: 4 MiB total, overlaps the 32 MiB x read.
  f4 w0, w1, w2, w3;
  if (mv) {
    const f4* wp = Wv4 + (size_t)(256 * s + kf) * D4 + 4 * cgv + dq;
    w0 = __builtin_nontemporal_load(wp);
    w1 = __builtin_nontemporal_load(wp + (size_t)64 * D4);
    w2 = __builtin_nontemporal_load(wp + (size_t)128 * D4);
    w3 = __builtin_nontemporal_load(wp + (size_t)192 * D4);
  }

  const unsigned ref = __hip_atomic_load(refw, __ATOMIC_RELAXED,
                                         __HIP_MEMORY_SCOPE_AGENT);
  const unsigned tgt = ref + 1u;

  // Phase 1: partial column sums.
  // Block (rg=b>>4, cg=b&15) sums rows [128rg,128rg+128) x cols [64cg,64cg+64).
  {
    const int rg = b >> 4;
    const int cg = b & 15;
    const int cl = t & 15;
    const int rl = t >> 4;
    const f4* p = x4 + (size_t)(128 * rg + rl) * D4 + 16 * cg + cl;
    f4 acc = {0.f, 0.f, 0.f, 0.f};
#pragma unroll
    for (int j = 0; j < 8; ++j)
      acc += __builtin_nontemporal_load(&p[(size_t)(16 * j) * D4]);
    red[t] = acc;                     // layout t = rl*16 + cl
    __syncthreads();
    if (t < 128) red[t] += red[t + 128];
    __syncthreads();
    if (t < 64)  red[t] += red[t + 64];
    __syncthreads();
    if (t < 32)  red[t] += red[t + 32];
    __syncthreads();
    // Publish, all within wave 0 (lanes 0-15 store, lane 0 flags), ordered by
    // program order + vmcnt(0). sc0 sc1 = write-through to the L3 coherence
    // point: no wbl2 anywhere.
    if (t < 16) {
      const f4 val = red[t] + red[t + 16];
      f4* dst = partial4 + (size_t)rg * D4 + 16 * cg + t;
      asm volatile(
          "global_store_dwordx4 %0, %1, off sc0 sc1\n\t"
          "s_waitcnt vmcnt(0)"
          :: "v"(dst), "v"(val) : "memory");
    }
    if (t == 0) {
      unsigned int* fp = &flags[b];
      asm volatile("global_store_dword %0, %1, off sc0 sc1"
                   :: "v"(fp), "v"(tgt) : "memory");
    }
  }

  // Level 1: ONLY block 0 polls the flag array, then raises the superflag.
  if (b == 0) {
    int good = 0;
    for (int it = 0; it < 200000; ++it) {   // bound; normal exit in ~6us
      const unsigned a0 = __hip_atomic_load(&flags[t], __ATOMIC_RELAXED,
                                            __HIP_MEMORY_SCOPE_AGENT);
      const unsigned a1 = __hip_atomic_load(&flags[t + 256], __ATOMIC_RELAXED,
                                            __HIP_MEMORY_SCOPE_AGENT);
      const unsigned a2 = __hip_atomic_load(&flags[t + 512], __ATOMIC_RELAXED,
                                            __HIP_MEMORY_SCOPE_AGENT);
      const unsigned a3 = __hip_atomic_load(&flags[t + 768], __ATOMIC_RELAXED,
                                            __HIP_MEMORY_SCOPE_AGENT);
      const int mine = (a0 == tgt) & (a1 == tgt) & (a2 == tgt) & (a3 == tgt);
      if (__syncthreads_and(mine)) { good = 1; break; }
      __builtin_amdgcn_s_sleep(4);
    }
    if (t == 0 && good) {
      // Flags observed in L3 => all partial data is in L3 (producers ordered
      // data before flag via vmcnt). Relaxed store, no wbl2.
      __hip_atomic_store(super, tgt, __ATOMIC_RELAXED,
                         __HIP_MEMORY_SCOPE_AGENT);
    }
  }
  if (!mv) return;

  // Level 2: one thread per mv block polls the single superflag word.
  if (t == 0) {
    int good = 0;
    for (int it = 0; it < 400000; ++it) {   // bound; normal exit in ~1-3us
      const unsigned sv = __hip_atomic_load(super, __ATOMIC_RELAXED,
                                            __HIP_MEMORY_SCOPE_AGENT);
      if (sv == tgt) { good = 1; break; }
      __builtin_amdgcn_s_sleep(6);
    }
    oks = good;   // no acquire: consumer reads below bypass L2 (sc0 sc1)
  }
  __syncthreads();
  const int ok = oks;

  // Step 1: reduce partial[64][k-range] -> cs4 via sc0 sc1 loads (read the
  // L3 coherence point directly; consumer XCD's L2 may hold stale poison).
  {
    const int rq = t >> 6;    // [0,4)
    const int gl = t & 63;    // [0,64)
    f4 a = {0.f, 0.f, 0.f, 0.f};
    if (ok) {
      const f4* base = partial4 + (size_t)(rq * 16) * D4 + 64 * s + gl;
#pragma unroll
      for (int batch = 0; batch < 4; ++batch) {
        f4 a0, a1, a2, a3;
        const f4* q0 = base + (size_t)(batch * 4 + 0) * D4;
        const f4* q1 = base + (size_t)(batch * 4 + 1) * D4;
        const f4* q2 = base + (size_t)(batch * 4 + 2) * D4;
        const f4* q3 = base + (size_t)(batch * 4 + 3) * D4;
        asm volatile(
            "global_load_dwordx4 %0, %4, off sc0 sc1\n\t"
            "global_load_dwordx4 %1, %5, off sc0 sc1\n\t"
            "global_load_dwordx4 %2, %6, off sc0 sc1\n\t"
            "global_load_dwordx4 %3, %7, off sc0 sc1\n\t"
            "s_waitcnt vmcnt(0)"
            : "=&v"(a0), "=&v"(a1), "=&v"(a2), "=&v"(a3)
            : "v"(q0), "v"(q1), "v"(q2), "v"(q3)
            : "memory");
        a += (a0 + a1) + (a2 + a3);
      }
    } else {
      // Correctness-only fallback (timeout path): sum column slice from x.
      for (int r = rq; r < NROWS; r += 4)
        a += x4[(size_t)r * D4 + 64 * s + gl];
    }
    tmp[rq][gl] = a;
  }
  __syncthreads();
  if (t < 64) {
    const float sc = 1.0f / (float)NROWS;
    cs4[t] = (tmp[0][t] + tmp[1][t] + tmp[2][t] + tmp[3][t]) * sc;
  }
  __syncthreads();

  // Step 2: matvec from prefetched registers; reduce over kf; write outsplit.
  const float* cs = (const float*)cs4;   // local k' in [0,256)
  f4 acc = {0.f, 0.f, 0.f, 0.f};
  acc += w0 * cs[kf];
  acc += w1 * cs[kf + 64];
  acc += w2 * cs[kf + 128];
  acc += w3 * cs[kf + 192];
  red[t] = acc;             // layout t = kf*4 + dq; reduce over kf
  __syncthreads();
  if (t < 128) red[t] += red[t + 128];   // kf+32
  __syncthreads();
  if (t < 64)  red[t] += red[t + 64];    // kf+16
  __syncthreads();
  if (t < 32)  red[t] += red[t + 32];    // kf+8
  __syncthreads();
  if (t < 16)  red[t] += red[t + 16];    // kf+4
  __syncthreads();
  if (t < 8)   red[t] += red[t + 8];     // kf+2
  __syncthreads();
  if (t < 4)   outsplit4[(size_t)s * D4 + 4 * cgv + t] = red[t] + red[t + 4];
  // outsplit handoff to bcast_k crosses a kernel boundary (stream-order
  // release/acquire) -> plain stores are fine.
}

// K3: sum 4 k-splits (16 KB, L2-hot, once per block) and broadcast into all
// rows. 2048 blocks, 4 rows/block, float4 NT stores (write-bound; the extra
// L2 reads hide under the slower HBM write path).
__global__ __launch_bounds__(256) void bcast_k(
    const f4* __restrict__ outsplit4, f4* __restrict__ out4) {
  const int t = threadIdx.x;
  const int b = blockIdx.x;
  const f4 v = (outsplit4[t] + outsplit4[D4 + t]) +
               (outsplit4[2 * D4 + t] + outsplit4[3 * D4 + t]);
  f4* p = out4 + (size_t)b * 4 * D4 + t;
#pragma unroll
  for (int r = 0; r < 4; ++r) {
    __builtin_nontemporal_store(v, &p[(size_t)r * D4]);
  }
}

extern "C" void kernel_launch(void* const* d_in, const int* in_sizes, int n_in,
                              void* d_out, int out_size, void* d_ws, size_t ws_size,
                              hipStream_t stream) {
  const float* x  = (const float*)d_in[0];
  // d_in[1] = Wq, d_in[2] = Wk provably unused (softmax exactly uniform).
  const float* Wv = (const float*)d_in[3];
  float* ws       = (float*)d_ws;
  float* partial  = ws;                           // 65536 floats (256 KB)
  float* outsplit = ws + (size_t)64 * DDIM;       // 4096 floats  (16 KB)
  unsigned int* flags = (unsigned int*)(ws + (size_t)68 * 1024);  // 1024 words
  unsigned int* super = flags + 1024;
  const unsigned int* refw = (const unsigned int*)(super + 1);

  hipLaunchKernelGGL(fused_k, dim3(1024), dim3(256), 0, stream,
                     (const f4*)x, (const f4*)Wv, (f4*)partial,
                     (f4*)outsplit, flags, super, refw);
  hipLaunchKernelGGL(bcast_k, dim3(2048), dim3(256), 0, stream,
                     (const f4*)outsplit, (f4*)d_out);
}

// Round 7
// 101.373 us; speedup vs baseline: 1.7551x; 1.0015x over previous
//
#include <hip/hip_runtime.h>

// out[i,:] = mean_j(x[j,:]) @ Wv for all i (softmax with 2^-50 scale is exactly
// uniform in fp32; exp(|s|<6e-13) == 1.0f exactly). Q/K/Wq/Wk are dead.
//
// R3: same-address agent RMWs serialize ~86ns -> zero atomics on hot paths.
// R4: ~83us fixed harness poison fills in the timed window; serial floor
//     ~12.5us (x-read 5.3 + matvec ~1 + out-write 5.3; no overlap possible).
// R5: split-K matvec, 3 kernels -> 99.6us.
// R6-R9: fused attempts stuck at 44us extra: agent RELEASE/ACQUIRE emit
//     buffer_wbl2/inv walks (128 serialized L2 walks per XCD ~= 44us).
// R10: zero cache-maintenance sync (sc0 sc1 write/read-through the L3
//     coherence point; intra-wave vmcnt ordering; no RELEASE/ACQUIRE) ->
//     101.5us, fused_k off the top-5. Theory confirmed.
// R11 (this round): single-kernel full fusion. Saves the bcast launch gap
//     (~2.5-3us) and switches consumer partial reads from forced-L3 sc0sc1
//     to NORMAL cached loads -- safe: consumer L2s were invalidated at the
//     previous kernel boundary and no block touches partial/outsplit before
//     its poll succeeds, so first access per XCD misses to L3 (fresh), rest
//     hit L2. Chain: colsum -> flags -> blk0 poll -> super1 -> 256 mv blocks
//     matvec -> flag2 -> blk0 poll -> super2 -> ALL 1024 blocks write 8 rows
//     each. Exactly-resident grid (1024 = 256 CU x 4), no circular waits.

#define NROWS 8192
#define DDIM  1024
#define D4    (DDIM / 4)   // 256 float4 groups per row

typedef float f4 __attribute__((ext_vector_type(4)));

// ws layout (floats):
//   partial  @ 0     : 64*1024 floats (256 KB)
//   outsplit @ 65536 : 4*1024 floats  (16 KB)
//   flags    @ 69632 : 1024 uint32 (one per block)
//   flag2    @ 70656 : 256 uint32 (one per mv block)
//   super1   @ 70912 : 1 uint32
//   super2   @ 70913 : 1 uint32
//   ref      @ 70914 : 1 uint32, never written (uniform poison base)

__global__ __launch_bounds__(256) void fused_all_k(
    const f4* __restrict__ x4, const f4* __restrict__ Wv4,
    f4* __restrict__ partial4, f4* __restrict__ outsplit4,
    unsigned int* __restrict__ flags, unsigned int* __restrict__ flag2,
    unsigned int* __restrict__ super1, unsigned int* __restrict__ super2,
    const unsigned int* __restrict__ refw, f4* __restrict__ out4) {
  __shared__ f4 red[256];     // 4 KB (colsum tree; matvec tree; fallback cs)
  __shared__ f4 tmp[4][64];   // 4 KB
  __shared__ f4 cs4[64];      // 1 KB
  __shared__ int oks, oks2;
  const int t = threadIdx.x;
  const int b = blockIdx.x;
  const bool mv = (b < 256);          // matvec-designated blocks
  const int s   = b & 3;              // k-split      (mv blocks)
  const int cgv = b >> 2;             // d-colgroup   (mv blocks, [0,64))
  const int kf  = t >> 2;             // [0,64)
  const int dq  = t & 3;              // [0,4)

  // Wv prefetch for mv blocks: 4 MiB total, overlaps the 32 MiB x read.
  f4 w0, w1, w2, w3;
  if (mv) {
    const f4* wp = Wv4 + (size_t)(256 * s + kf) * D4 + 4 * cgv + dq;
    w0 = __builtin_nontemporal_load(wp);
    w1 = __builtin_nontemporal_load(wp + (size_t)64 * D4);
    w2 = __builtin_nontemporal_load(wp + (size_t)128 * D4);
    w3 = __builtin_nontemporal_load(wp + (size_t)192 * D4);
  }

  const unsigned ref = __hip_atomic_load(refw, __ATOMIC_RELAXED,
                                         __HIP_MEMORY_SCOPE_AGENT);
  const unsigned tgt = ref + 1u;

  // Phase 1: partial column sums.
  // Block (rg=b>>4, cg=b&15) sums rows [128rg,128rg+128) x cols [64cg,64cg+64).
  {
    const int rg = b >> 4;
    const int cg = b & 15;
    const int cl = t & 15;
    const int rl = t >> 4;
    const f4* p = x4 + (size_t)(128 * rg + rl) * D4 + 16 * cg + cl;
    f4 acc = {0.f, 0.f, 0.f, 0.f};
#pragma unroll
    for (int j = 0; j < 8; ++j)
      acc += __builtin_nontemporal_load(&p[(size_t)(16 * j) * D4]);
    red[t] = acc;                     // layout t = rl*16 + cl
    __syncthreads();
    if (t < 128) red[t] += red[t + 128];
    __syncthreads();
    if (t < 64)  red[t] += red[t + 64];
    __syncthreads();
    if (t < 32)  red[t] += red[t + 32];
    __syncthreads();
    // Publish within wave 0: sc0 sc1 write-through to L3, vmcnt(0), then the
    // flag store. Intra-wave program order is the only fence (R10-proven).
    if (t < 16) {
      const f4 val = red[t] + red[t + 16];
      f4* dst = partial4 + (size_t)rg * D4 + 16 * cg + t;
      asm volatile(
          "global_store_dwordx4 %0, %1, off sc0 sc1\n\t"
          "s_waitcnt vmcnt(0)"
          :: "v"(dst), "v"(val) : "memory");
    }
    if (t == 0) {
      unsigned int* fp = &flags[b];
      asm volatile("global_store_dword %0, %1, off sc0 sc1"
                   :: "v"(fp), "v"(tgt) : "memory");
    }
    __syncthreads();   // red[] reused below
  }

  // Level 1: ONLY block 0 polls the flag array, then raises superflag1.
  if (b == 0) {
    int good = 0;
    for (int it = 0; it < 200000; ++it) {
      const unsigned a0 = __hip_atomic_load(&flags[t], __ATOMIC_RELAXED,
                                            __HIP_MEMORY_SCOPE_AGENT);
      const unsigned a1 = __hip_atomic_load(&flags[t + 256], __ATOMIC_RELAXED,
                                            __HIP_MEMORY_SCOPE_AGENT);
      const unsigned a2 = __hip_atomic_load(&flags[t + 512], __ATOMIC_RELAXED,
                                            __HIP_MEMORY_SCOPE_AGENT);
      const unsigned a3 = __hip_atomic_load(&flags[t + 768], __ATOMIC_RELAXED,
                                            __HIP_MEMORY_SCOPE_AGENT);
      const int mine = (a0 == tgt) & (a1 == tgt) & (a2 == tgt) & (a3 == tgt);
      if (__syncthreads_and(mine)) { good = 1; break; }
      __builtin_amdgcn_s_sleep(4);
    }
    if (t == 0 && good) {
      // Flags in L3 => all partial data in L3 (producer vmcnt ordering).
      __hip_atomic_store(super1, tgt, __ATOMIC_RELAXED,
                         __HIP_MEMORY_SCOPE_AGENT);
    }
  }

  // Phase 2 (mv blocks): reduce partial -> cs4, matvec, publish outsplit.
  if (mv) {
    if (t == 0) {
      int good = 0;
      for (int it = 0; it < 400000; ++it) {
        const unsigned sv = __hip_atomic_load(super1, __ATOMIC_RELAXED,
                                              __HIP_MEMORY_SCOPE_AGENT);
        if (sv == tgt) { good = 1; break; }
        __builtin_amdgcn_s_sleep(6);
      }
      oks = good;
    }
    __syncthreads();
    const int ok = oks;

    // partial reduce via NORMAL cached loads: first touch per XCD misses to
    // L3 (fresh; L2s boundary-invalidated, nobody read partial pre-flag),
    // later mv blocks on the same XCD hit L2.
    {
      const int rq = t >> 6;    // [0,4)
      const int gl = t & 63;    // [0,64)
      f4 a = {0.f, 0.f, 0.f, 0.f};
      if (ok) {
#pragma unroll
        for (int m = 0; m < 16; ++m)
          a += partial4[(size_t)(rq * 16 + m) * D4 + 64 * s + gl];
      } else {
        // Correctness-only fallback (timeout): sum column slice from x.
        for (int r = rq; r < NROWS; r += 4)
          a += x4[(size_t)r * D4 + 64 * s + gl];
      }
      tmp[rq][gl] = a;
    }
    __syncthreads();
    if (t < 64) {
      const float sc = 1.0f / (float)NROWS;
      cs4[t] = (tmp[0][t] + tmp[1][t] + tmp[2][t] + tmp[3][t]) * sc;
    }
    __syncthreads();

    const float* cs = (const float*)cs4;   // local k' in [0,256)
    f4 acc = {0.f, 0.f, 0.f, 0.f};
    acc += w0 * cs[kf];
    acc += w1 * cs[kf + 64];
    acc += w2 * cs[kf + 128];
    acc += w3 * cs[kf + 192];
    red[t] = acc;             // layout t = kf*4 + dq; reduce over kf
    __syncthreads();
    if (t < 128) red[t] += red[t + 128];   // kf+32
    __syncthreads();
    if (t < 64)  red[t] += red[t + 64];    // kf+16
    __syncthreads();
    if (t < 32)  red[t] += red[t + 32];    // kf+8
    __syncthreads();
    if (t < 16)  red[t] += red[t + 16];    // kf+4
    __syncthreads();
    if (t < 8)   red[t] += red[t + 8];     // kf+2
    __syncthreads();
    // Publish outsplit (wave 0: sc0 sc1 stores, vmcnt, flag2).
    if (t < 4) {
      const f4 val = red[t] + red[t + 4];
      f4* dst = outsplit4 + (size_t)s * D4 + 4 * cgv + t;
      asm volatile(
          "global_store_dwordx4 %0, %1, off sc0 sc1\n\t"
          "s_waitcnt vmcnt(0)"
          :: "v"(dst), "v"(val) : "memory");
    }
    if (t == 0) {
      unsigned int* fp = &flag2[b];
      asm volatile("global_store_dword %0, %1, off sc0 sc1"
                   :: "v"(fp), "v"(tgt) : "memory");
    }
    __syncthreads();   // red[] maybe reused in fallback below
  }

  // Level 2: ONLY block 0 polls flag2[256], then raises superflag2.
  if (b == 0) {
    int good = 0;
    for (int it = 0; it < 200000; ++it) {
      const unsigned a0 = __hip_atomic_load(&flag2[t], __ATOMIC_RELAXED,
                                            __HIP_MEMORY_SCOPE_AGENT);
      if (__syncthreads_and(a0 == tgt)) { good = 1; break; }
      __builtin_amdgcn_s_sleep(4);
    }
    if (t == 0 && good) {
      __hip_atomic_store(super2, tgt, __ATOMIC_RELAXED,
                         __HIP_MEMORY_SCOPE_AGENT);
    }
  }

  // Phase 3: ALL 1024 blocks: wait for superflag2, then write 8 rows each.
  if (t == 0) {
    int good = 0;
    for (int it = 0; it < 400000; ++it) {
      const unsigned sv = __hip_atomic_load(super2, __ATOMIC_RELAXED,
                                            __HIP_MEMORY_SCOPE_AGENT);
      if (sv == tgt) { good = 1; break; }
      __builtin_amdgcn_s_sleep(6);
    }
    oks2 = good;
  }
  __syncthreads();

  f4 v;
  if (oks2) {
    // Normal loads: outsplit lines are L3-fresh (sc0 sc1 published), first
    // touch per XCD misses to L3, then L2-hot for the other ~127 blocks.
    v = (outsplit4[t] + outsplit4[D4 + t]) +
        (outsplit4[2 * D4 + t] + outsplit4[3 * D4 + t]);
  } else {
    // Correctness-only fallback (timeout; never taken in practice): full
    // local recompute of outrow column t.
    f4 a = {0.f, 0.f, 0.f, 0.f};
    for (int r = 0; r < NROWS; ++r) a += x4[(size_t)r * D4 + t];
    const float sc = 1.0f / (float)NROWS;
    red[t] = a * sc;
    __syncthreads();   // block-uniform branch (oks2 uniform)
    const float* c = (const float*)red;
    f4 acc = {0.f, 0.f, 0.f, 0.f};
    for (int k = 0; k < DDIM; ++k)
      acc += c[k] * Wv4[(size_t)k * D4 + t];
    v = acc;
  }
  // Block b writes rows [8b, 8b+8): wave = 64 consecutive float4 = 1 KB.
  f4* p = out4 + (size_t)b * 8 * D4 + t;
#pragma unroll
  for (int r = 0; r < 8; ++r) {
    __builtin_nontemporal_store(v, &p[(size_t)r * D4]);
  }
}

extern "C" void kernel_launch(void* const* d_in, const int* in_sizes, int n_in,
                              void* d_out, int out_size, void* d_ws, size_t ws_size,
                              hipStream_t stream) {
  const float* x  = (const float*)d_in[0];
  // d_in[1] = Wq, d_in[2] = Wk provably unused (softmax exactly uniform).
  const float* Wv = (const float*)d_in[3];
  float* ws       = (float*)d_ws;
  float* partial  = ws;                           // 65536 floats (256 KB)
  float* outsplit = ws + (size_t)64 * DDIM;       // 4096 floats  (16 KB)
  unsigned int* flags  = (unsigned int*)(ws + (size_t)68 * 1024);  // 1024
  unsigned int* flag2  = flags + 1024;                             // 256
  unsigned int* super1 = flag2 + 256;
  unsigned int* super2 = super1 + 1;
  const unsigned int* refw = (const unsigned int*)(super2 + 1);

  hipLaunchKernelGGL(fused_all_k, dim3(1024), dim3(256), 0, stream,
                     (const f4*)x, (const f4*)Wv, (f4*)partial,
                     (f4*)outsplit, flags, flag2, super1, super2, refw,
                     (f4*)d_out);
}